// Round 1
// baseline (334.461 us; speedup 1.0000x reference)
//
#include <hip/hip_runtime.h>

// Bilinear spatial-transformer sampler.
// X: [16, 512, 512, 16] f32 (NHWC), theta: [16, 6] f32
// out: [16, 256, 256, 16] f32
//
// Thread mapping: tid = ((b*256 + oy)*256 + ox)*4 + c4, c4 = channel quad.
// Each thread computes the sample coordinate for its pixel (redundant x4,
// cheap vs. the gather) and blends 4 gathered float4 corners.

#define IN_H 512
#define IN_W 512
#define OUT_HW_BITS 8   // 256
#define NCH 16

__global__ __launch_bounds__(256) void bilerp_kernel(
    const float* __restrict__ X,
    const float* __restrict__ theta,
    float* __restrict__ out)
{
    const int tid = blockIdx.x * blockDim.x + threadIdx.x;
    const int c4 = tid & 3;          // which float4 of the 16 channels
    const int p  = tid >> 2;         // global pixel index
    const int ox = p & 255;
    const int oy = (p >> OUT_HW_BITS) & 255;
    const int b  = p >> (2 * OUT_HW_BITS);

    // linspace(-1, 1, 256): -1 + i * (2/255)
    const float xc = fmaf((float)ox, 2.0f / 255.0f, -1.0f);
    const float yc = fmaf((float)oy, 2.0f / 255.0f, -1.0f);

    const float* t = theta + b * 6;
    const float xs = fmaf(t[0], xc, fmaf(t[1], yc, t[2]));
    const float ys = fmaf(t[3], xc, fmaf(t[4], yc, t[5]));

    // 0.5*(v+1)*512 == (v+1)*256 exactly (power-of-2 scales)
    const float x = (xs + 1.0f) * 256.0f;
    const float y = (ys + 1.0f) * 256.0f;

    // truncation toward zero, matching astype(int32)
    int x0 = (int)x;
    int y0 = (int)y;
    int x1 = x0 + 1;
    int y1 = y0 + 1;
    x0 = min(max(x0, 0), IN_W - 1);
    x1 = min(max(x1, 0), IN_W - 1);
    y0 = min(max(y0, 0), IN_H - 1);
    y1 = min(max(y1, 0), IN_H - 1);

    // weights from CLAMPED coords (reference clips before float-casting)
    const float x0f = (float)x0, x1f = (float)x1;
    const float y0f = (float)y0, y1f = (float)y1;
    const float wa = (x1f - x) * (y1f - y);
    const float wb = (x1f - x) * (y - y0f);
    const float wc = (x - x0f) * (y1f - y);
    const float wd = (x - x0f) * (y - y0f);

    // gather 4 corners, float4 of channels [4*c4, 4*c4+4)
    const float4* Xb = (const float4*)(X + (size_t)b * (IN_H * IN_W * NCH));
    const int ia = (y0 * IN_W + x0) * 4 + c4;
    const int ib = (y1 * IN_W + x0) * 4 + c4;
    const int ic = (y0 * IN_W + x1) * 4 + c4;
    const int id = (y1 * IN_W + x1) * 4 + c4;

    const float4 pa = Xb[ia];
    const float4 pb = Xb[ib];
    const float4 pc = Xb[ic];
    const float4 pd = Xb[id];

    float4 o;
    o.x = fmaf(wa, pa.x, fmaf(wb, pb.x, fmaf(wc, pc.x, wd * pd.x)));
    o.y = fmaf(wa, pa.y, fmaf(wb, pb.y, fmaf(wc, pc.y, wd * pd.y)));
    o.z = fmaf(wa, pa.z, fmaf(wb, pb.z, fmaf(wc, pc.z, wd * pd.z)));
    o.w = fmaf(wa, pa.w, fmaf(wb, pb.w, fmaf(wc, pc.w, wd * pd.w)));

    ((float4*)out)[tid] = o;
}

extern "C" void kernel_launch(void* const* d_in, const int* in_sizes, int n_in,
                              void* d_out, int out_size, void* d_ws, size_t ws_size,
                              hipStream_t stream) {
    const float* X     = (const float*)d_in[0];
    const float* theta = (const float*)d_in[1];
    float* out = (float*)d_out;

    // total threads = 16 * 256 * 256 * 4 = 4,194,304 -> 16384 blocks of 256
    const int total = 16 * 256 * 256 * 4;
    const int block = 256;
    const int grid = total / block;
    bilerp_kernel<<<grid, block, 0, stream>>>(X, theta, out);
}

// Round 2
// 334.012 us; speedup vs baseline: 1.0013x; 1.0013x over previous
//
#include <hip/hip_runtime.h>

// Bilinear spatial-transformer sampler.
// X: [16, 512, 512, 16] f32 (NHWC), theta: [16, 6] f32
// out: [16, 256, 256, 16] f32
//
// Block = one 8x8 output-pixel tile of one batch (256 threads, 4 lanes per
// pixel, each lane owns a float4 of the 16 channels). The tile's gather
// footprint is a compact ~13x13-px input neighborhood -> corner overlap
// between adjacent ox/oy pixels hits L1 on the same CU.
// blockIdx is swizzled so each XCD gets a contiguous slab of tiles (L2
// locality); output stores are non-temporal (write-once, keep L2 for gathers).

#define IN_H 512
#define IN_W 512
#define NCH 16

typedef float v4f __attribute__((ext_vector_type(4)));

__global__ __launch_bounds__(256) void bilerp_kernel(
    const float* __restrict__ X,
    const float* __restrict__ theta,
    float* __restrict__ out)
{
    // --- XCD slab swizzle: grid = 16384 blocks; consecutive hardware
    // dispatch round-robins XCDs, so (bid & 7) selects the XCD and we give
    // each XCD a contiguous range of tiles.
    const int G = gridDim.x;            // 16384
    const int slab = G >> 3;            // blocks per XCD slab
    const int bid = blockIdx.x;
    const int eff = (bid & 7) * slab + (bid >> 3);

    const int b    = eff >> 10;         // 1024 tiles per batch (32x32 tiles)
    const int tile = eff & 1023;
    const int tx   = tile & 31;
    const int ty   = tile >> 5;

    const int t  = threadIdx.x;
    const int c4 = t & 3;               // which float4 of the 16 channels
    const int px = (t >> 2) & 7;
    const int py = t >> 5;

    const int ox = (tx << 3) + px;
    const int oy = (ty << 3) + py;

    // linspace(-1, 1, 256): -1 + i * (2/255)
    const float xc = fmaf((float)ox, 2.0f / 255.0f, -1.0f);
    const float yc = fmaf((float)oy, 2.0f / 255.0f, -1.0f);

    const float* th = theta + b * 6;    // b is wave-uniform -> s_loads
    const float xs = fmaf(th[0], xc, fmaf(th[1], yc, th[2]));
    const float ys = fmaf(th[3], xc, fmaf(th[4], yc, th[5]));

    // 0.5*(v+1)*512 == (v+1)*256 exactly (power-of-2 scales)
    const float x = (xs + 1.0f) * 256.0f;
    const float y = (ys + 1.0f) * 256.0f;

    // truncation toward zero, matching astype(int32)
    int x0 = (int)x;
    int y0 = (int)y;
    int x1 = x0 + 1;
    int y1 = y0 + 1;
    x0 = min(max(x0, 0), IN_W - 1);
    x1 = min(max(x1, 0), IN_W - 1);
    y0 = min(max(y0, 0), IN_H - 1);
    y1 = min(max(y1, 0), IN_H - 1);

    // weights from CLAMPED coords (reference clips before float-casting)
    const float x0f = (float)x0, x1f = (float)x1;
    const float y0f = (float)y0, y1f = (float)y1;
    const float wa = (x1f - x) * (y1f - y);
    const float wb = (x1f - x) * (y - y0f);
    const float wc = (x - x0f) * (y1f - y);
    const float wd = (x - x0f) * (y - y0f);

    // gather 4 corners, float4 of channels [4*c4, 4*c4+4)
    const v4f* Xb = (const v4f*)(X + (size_t)b * (IN_H * IN_W * NCH));
    const int ia = (y0 * IN_W + x0) * 4 + c4;
    const int ib = (y1 * IN_W + x0) * 4 + c4;
    const int ic = (y0 * IN_W + x1) * 4 + c4;
    const int id = (y1 * IN_W + x1) * 4 + c4;

    const v4f pa = Xb[ia];
    const v4f pb = Xb[ib];
    const v4f pc = Xb[ic];
    const v4f pd = Xb[id];

    v4f o;
    o.x = fmaf(wa, pa.x, fmaf(wb, pb.x, fmaf(wc, pc.x, wd * pd.x)));
    o.y = fmaf(wa, pa.y, fmaf(wb, pb.y, fmaf(wc, pc.y, wd * pd.y)));
    o.z = fmaf(wa, pa.z, fmaf(wb, pb.z, fmaf(wc, pc.z, wd * pd.z)));
    o.w = fmaf(wa, pa.w, fmaf(wb, pb.w, fmaf(wc, pc.w, wd * pd.w)));

    // output float4 index: ((b*256 + oy)*256 + ox)*4 + c4
    const int oidx = (((b << 8) + oy) << 8) * 4 + (ox << 2) + c4;
    __builtin_nontemporal_store(o, (v4f*)out + oidx);
}

extern "C" void kernel_launch(void* const* d_in, const int* in_sizes, int n_in,
                              void* d_out, int out_size, void* d_ws, size_t ws_size,
                              hipStream_t stream) {
    const float* X     = (const float*)d_in[0];
    const float* theta = (const float*)d_in[1];
    float* out = (float*)d_out;

    // 16 batches * 32*32 tiles = 16384 blocks of 256 threads
    const int grid = 16 * 32 * 32;
    bilerp_kernel<<<grid, 256, 0, stream>>>(X, theta, out);
}

// Round 3
// 331.812 us; speedup vs baseline: 1.0080x; 1.0066x over previous
//
#include <hip/hip_runtime.h>

// Bilinear spatial-transformer sampler.
// X: [16, 512, 512, 16] f32 (NHWC), theta: [16, 6] f32
// out: [16, 256, 256, 16] f32
//
// Key insight: theta ~ N(0,1) puts ~80% of samples out of bounds. The
// reference's clip-before-weight construction makes those outputs exactly 0
// (clamped coords give exactly-negated weight pairs applied to identical
// gathered values; the ref's left-to-right sum cancels bit-exactly in
// double-clamped zones and to ~ulp residue in single-clamped ones).
// So: when x0c==x1c || y0c==y1c, store 0 and SKIP all four gathers.
// This removes ~80% of the scattered-gather work (the real bottleneck) and
// tightens absmax (our fmaf chain previously left ~0.09 residue where the
// ref cancels to 0).
//
// Thread mapping (R0-style linear; 2D tiling measured neutral in R2 —
// stride ~2px means no corner sharing between adjacent pixels):
// tid = ((b*256 + oy)*256 + ox)*4 + c4, c4 = channel quad.

#define IN_H 512
#define IN_W 512
#define NCH 16

typedef float v4f __attribute__((ext_vector_type(4)));

__global__ __launch_bounds__(256) void bilerp_kernel(
    const float* __restrict__ X,
    const float* __restrict__ theta,
    float* __restrict__ out)
{
    const int tid = blockIdx.x * blockDim.x + threadIdx.x;
    const int c4 = tid & 3;          // which float4 of the 16 channels
    const int p  = tid >> 2;         // global pixel index
    const int ox = p & 255;
    const int oy = (p >> 8) & 255;
    const int b  = p >> 16;

    // linspace(-1, 1, 256): -1 + i * (2/255)
    const float xc = fmaf((float)ox, 2.0f / 255.0f, -1.0f);
    const float yc = fmaf((float)oy, 2.0f / 255.0f, -1.0f);

    const float* t = theta + b * 6;  // b uniform per block -> scalar loads
    const float xs = fmaf(t[0], xc, fmaf(t[1], yc, t[2]));
    const float ys = fmaf(t[3], xc, fmaf(t[4], yc, t[5]));

    // 0.5*(v+1)*512 == (v+1)*256 exactly (power-of-2 scales)
    const float x = (xs + 1.0f) * 256.0f;
    const float y = (ys + 1.0f) * 256.0f;

    // truncation toward zero, matching astype(int32)
    const int x0 = (int)x;
    const int y0 = (int)y;
    const int x0c = min(max(x0, 0), IN_W - 1);
    const int x1c = min(max(x0 + 1, 0), IN_W - 1);
    const int y0c = min(max(y0, 0), IN_H - 1);
    const int y1c = min(max(y0 + 1, 0), IN_H - 1);

    v4f o = {0.0f, 0.0f, 0.0f, 0.0f};

    // If either axis is fully clamped, the reference's weights cancel to
    // (near-)exact zero -> emit 0, skip the gathers entirely.
    if (x0c != x1c && y0c != y1c) {
        // weights from CLAMPED coords (reference clips before float-casting)
        const float x0f = (float)x0c, x1f = (float)x1c;
        const float y0f = (float)y0c, y1f = (float)y1c;
        const float wa = (x1f - x) * (y1f - y);
        const float wb = (x1f - x) * (y - y0f);
        const float wc = (x - x0f) * (y1f - y);
        const float wd = (x - x0f) * (y - y0f);

        const v4f* Xb = (const v4f*)(X + (size_t)b * (IN_H * IN_W * NCH));
        const int ia = (y0c * IN_W + x0c) * 4 + c4;
        const int ib = (y1c * IN_W + x0c) * 4 + c4;
        const int ic = (y0c * IN_W + x1c) * 4 + c4;
        const int id = (y1c * IN_W + x1c) * 4 + c4;

        const v4f pa = Xb[ia];
        const v4f pb = Xb[ib];
        const v4f pc = Xb[ic];
        const v4f pd = Xb[id];

        o.x = fmaf(wa, pa.x, fmaf(wb, pb.x, fmaf(wc, pc.x, wd * pd.x)));
        o.y = fmaf(wa, pa.y, fmaf(wb, pb.y, fmaf(wc, pc.y, wd * pd.y)));
        o.z = fmaf(wa, pa.z, fmaf(wb, pb.z, fmaf(wc, pc.z, wd * pd.z)));
        o.w = fmaf(wa, pa.w, fmaf(wb, pb.w, fmaf(wc, pc.w, wd * pd.w)));
    }

    __builtin_nontemporal_store(o, (v4f*)out + tid);
}

extern "C" void kernel_launch(void* const* d_in, const int* in_sizes, int n_in,
                              void* d_out, int out_size, void* d_ws, size_t ws_size,
                              hipStream_t stream) {
    const float* X     = (const float*)d_in[0];
    const float* theta = (const float*)d_in[1];
    float* out = (float*)d_out;

    // total threads = 16 * 256 * 256 * 4 = 4,194,304 -> 16384 blocks of 256
    const int total = 16 * 256 * 256 * 4;
    const int block = 256;
    bilerp_kernel<<<total / block, block, 0, stream>>>(X, theta, out);
}